// Round 11
// baseline (238.107 us; speedup 1.0000x reference)
//
#include <hip/hip_runtime.h>
#include <math.h>

#define EPSF 1e-5f
#define MAXNF (1.0f - 1e-5f)

constexpr int SEGc = 24;
constexpr int Nn   = 14;          // L / SEG
constexpr int NS   = Nn * SEGc;   // 336
constexpr int Tt   = 4;           // horizons
constexpr int Bb   = 32;
constexpr int Ll   = 336;
constexpr int Ff   = 256;
constexpr int Dd   = 128;
constexpr int Hh   = 256;
constexpr int BFc  = Bb * Ff;     // 8192

// v_init weight norm: 1 / (sum_{i=0}^{12} 0.9^i * 13)
constexpr float WNORM = 1.0f / (7.458134171670999f * 13.0f);
constexpr float LN09  = -0.10536051565782628f;   // ln(0.9)

// ---- packed fp32 (v_pk_fma_f32 on gfx90a+) ----
typedef float v2f __attribute__((ext_vector_type(2)));
__device__ __forceinline__ v2f vset(float a, float b){ v2f r; r.x=a; r.y=b; return r; }
__device__ __forceinline__ v2f vsplat(float s){ v2f r; r.x=s; r.y=s; return r; }
__device__ __forceinline__ v2f vfma(v2f a, v2f b, v2f c){
#if __has_builtin(__builtin_elementwise_fma)
    return __builtin_elementwise_fma(a, b, c);
#else
    return vset(fmaf(a.x, b.x, c.x), fmaf(a.y, b.y, c.y));
#endif
}
__device__ __forceinline__ v2f vfmas(float a, v2f b, v2f c){ return vfma(vsplat(a), b, c); }

// ---- fast math (tolerance 1.8e-2; these are ~1e-7 relative) ----
__device__ __forceinline__ float frcp(float x)  { return __builtin_amdgcn_rcpf(x); }
__device__ __forceinline__ float fsqrtf_(float x){ return __builtin_amdgcn_sqrtf(x); }
__device__ __forceinline__ float ftanh_pos(float x) {       // x >= 0
    const float e = __expf(fminf(2.f * x, 30.f));           // v_exp_f32
    return (e - 1.f) * frcp(e + 1.f);
}
__device__ __forceinline__ float fatanh01(float x) {        // 0 <= x <= MAXNF
    return 0.5f * __logf((1.f + x) * frcp(1.f - x));        // v_log_f32
}

// ---------------- fused kernel: one block (4 waves) per bf PAIR ----------------
// R10 structure, but barriers cut 6 -> 3:
//  * stats computed per-wave from global (bit-identical across waves; L2-warm)
//    while the wave stages its OWN component into a wave-private LDS slab
//    (no B1/B2);
//  * bc broadcast is wave-private LDS (same-wave DS ordering; no B3);
//  * zfl lives in the wave's own slab (aliases its dead xs via true data
//    dependence), so the first cross-wave handoff is the fusion read (B4).
// Waves run stats->encoder->logmap->vel->horizons fully unsynchronized.
__global__ __launch_bounds__(256, 4) void fused_kernel(
    const float* __restrict__ trend, const float* __restrict__ scoarse,
    const float* __restrict__ sfine, const float* __restrict__ resid,
    const float* __restrict__ revin_w, const float* __restrict__ revin_b,
    const float* __restrict__ enc_W, const float* __restrict__ enc_b,
    const float* __restrict__ vel_W, const float* __restrict__ vel_b,
    const float* __restrict__ steps, const float* __restrict__ mobius_w,
    const float* __restrict__ rec_W1, const float* __restrict__ rec_b1,
    const float* __restrict__ rec_W2, const float* __restrict__ rec_b2,
    float* __restrict__ out, float* __restrict__ hpart)
{
    // XCD-chunking swizzle over 4096 pair-blocks (8 XCDs x 512 chunk).
    const int bid   = blockIdx.x;
    const int kpair = ((bid & 7) << 9) | (bid >> 3);   // 0..4095
    const int bf0   = kpair << 1;
    const int b     = bf0 >> 8;
    const int f0    = bf0 & 255;          // even
    const int tid   = threadIdx.x;
    const int wid   = tid >> 6;           // 0..3 = component
    const int lane  = tid & 63;
    const int gi    = lane & 15;          // item index within group
    const int pg    = (lane >> 4) & 1;    // group p (meaningful for lanes 0..31)

    // lds_big: 4 wave-slabs of 1024 floats. Per wave c:
    //   xs  (staging): [c*1024 + p*336, +336)          (672 used)
    //   zfl (z_fut):   [c*1024 + (p*4+t)*128, +128)    (1024 used, after xs dead)
    // After B5 the whole region is reused as hbuf2 [t][Hh][p] (2048 floats).
    __shared__ float lds_big[4 * 1024];          // 16 KB, time-shared
    __shared__ float bcu[8 * Dd];                // [p][c]Dd bc; later uls2 [t][Dd][p]
    __shared__ float zfns[2][4][Tt];             // clipped norms per p

#define XSW(p)        (lds_big + c * 1024 + (p) * NS)
#define ZFL2(cc, p, t)(lds_big + (cc) * 1024 + ((p) * 4 + (t)) * Dd)

    const int c = wid;

    // ---- per-wave stats over the combined signal + stage own component ----
    float s0 = 0.f, q0 = 0.f, s1 = 0.f, q1 = 0.f;
    {
        float* xs0 = XSW(0);
        float* xs1 = XSW(1);
#pragma unroll 1
        for (int l = lane; l < NS; l += 64) {
            const int gidx = (b * Ll + l) * Ff + f0;
            const float2 vt = *reinterpret_cast<const float2*>(&trend[gidx]);
            const float2 vc = *reinterpret_cast<const float2*>(&scoarse[gidx]);
            const float2 vf = *reinterpret_cast<const float2*>(&sfine[gidx]);
            const float2 vr = *reinterpret_cast<const float2*>(&resid[gidx]);
            const float x0 = vt.x + vc.x + vf.x + vr.x;
            const float x1 = vt.y + vc.y + vf.y + vr.y;
            s0 += x0; q0 += x0 * x0; s1 += x1; q1 += x1 * x1;
            float2 own = vt;
            own = (c == 1) ? vc : own;
            own = (c == 2) ? vf : own;
            own = (c == 3) ? vr : own;
            xs0[l] = own.x;
            xs1[l] = own.y;
        }
    }
#pragma unroll 1
    for (int off = 1; off < 64; off <<= 1) {
        s0 += __shfl_xor(s0, off, 64); q0 += __shfl_xor(q0, off, 64);
        s1 += __shfl_xor(s1, off, 64); q1 += __shfl_xor(q1, off, 64);
    }
    const float mean0 = s0 * (1.f / (float)NS);
    const float stdv0 = fsqrtf_(q0 * (1.f / (float)NS) - mean0 * mean0 + 1e-5f);
    const float mean1 = s1 * (1.f / (float)NS);
    const float stdv1 = fsqrtf_(q1 * (1.f / (float)NS) - mean1 * mean1 + 1e-5f);
    const float rw0v = revin_w[f0],     rb0v = revin_b[f0];
    const float rw1v = revin_w[f0 + 1], rb1v = revin_b[f0 + 1];
    const float aff0 = frcp(stdv0) * rw0v;
    const float kaf0 = 0.25f * (rb0v - mean0 * aff0);
    const float aff1 = frcp(stdv1) * rw1v;
    const float kaf1 = 0.25f * (rb1v - mean1 * aff1);

    // ================= branch (component c = wid, both bf) =================
    const float4* xv40 = reinterpret_cast<const float4*>(XSW(0));
    const float4* xv41 = reinterpret_cast<const float4*>(XSW(1));
    const float* Wep = enc_W + c * SEGc * Dd + 2 * lane;
    const float* Wvp = vel_W + c * Dd * Dd + 2 * lane;

    v2f wreg[SEGc];
#pragma unroll
    for (int s = 0; s < SEGc; ++s)
        wreg[s] = *reinterpret_cast<const v2f*>(Wep + s * Dd);
    const v2f bev = *reinterpret_cast<const v2f*>(enc_b + c * Dd + 2 * lane);
    const v2f bvv = *reinterpret_cast<const v2f*>(vel_b + c * Dd + 2 * lane);

    v2f csv = vsplat(0.f);
#pragma unroll
    for (int s = 0; s < SEGc; ++s) csv += wreg[s];
    const v2f kb0v = vfmas(kaf0, csv, bev);
    const v2f kb1v = vfmas(kaf1, csv, bev);

    // --- Phase A: 28 encoder dots (14 per bf), packed dims ---
    v2f y0v[Nn], y1v[Nn];
#pragma unroll
    for (int n = 0; n < Nn; ++n) {
        v2f a0 = vsplat(0.f), a1 = vsplat(0.f);
#pragma unroll
        for (int q = 0; q < SEGc / 4; ++q) {
            const float4 xa = xv40[n * (SEGc / 4) + q];
            const float4 xb = xv41[n * (SEGc / 4) + q];
            a0 = vfmas(xa.x, wreg[4*q+0], a0); a1 = vfmas(xb.x, wreg[4*q+0], a1);
            a0 = vfmas(xa.y, wreg[4*q+1], a0); a1 = vfmas(xb.y, wreg[4*q+1], a1);
            a0 = vfmas(xa.z, wreg[4*q+2], a0); a1 = vfmas(xb.z, wreg[4*q+2], a1);
            a0 = vfmas(xa.w, wreg[4*q+3], a0); a1 = vfmas(xb.w, wreg[4*q+3], a1);
        }
        y0v[n] = vfmas(aff0, a0, kb0v);
        y1v[n] = vfmas(aff1, a1, kb1v);
    }

    // --- |y_n|^2 and neighbor dots for both bf: ONE rolled butterfly (54 vals) ---
    float qnv[2][Nn], rdv[2][Nn - 1];
#pragma unroll
    for (int n = 0; n < Nn; ++n) {
        qnv[0][n] = fmaf(y0v[n].y, y0v[n].y, y0v[n].x * y0v[n].x);
        qnv[1][n] = fmaf(y1v[n].y, y1v[n].y, y1v[n].x * y1v[n].x);
    }
#pragma unroll
    for (int n = 1; n < Nn; ++n) {
        rdv[0][n - 1] = fmaf(y0v[n-1].y, y0v[n].y, y0v[n-1].x * y0v[n].x);
        rdv[1][n - 1] = fmaf(y1v[n-1].y, y1v[n].y, y1v[n-1].x * y1v[n].x);
    }
#pragma unroll 1
    for (int off = 1; off < 64; off <<= 1) {
#pragma unroll
        for (int n = 0; n < Nn; ++n) {
            qnv[0][n] += __shfl_xor(qnv[0][n], off, 64);
            qnv[1][n] += __shfl_xor(qnv[1][n], off, 64);
        }
#pragma unroll
        for (int j = 0; j < Nn - 1; ++j) {
            rdv[0][j] += __shfl_xor(rdv[0][j], off, 64);
            rdv[1][j] += __shfl_xor(rdv[1][j], off, 64);
        }
    }
    float qsel0 = qnv[0][0], qsel1 = qnv[1][0];
#pragma unroll
    for (int n = 1; n < Nn; ++n) {
        qsel0 = (gi == n) ? qnv[0][n] : qsel0;
        qsel1 = (gi == n) ? qnv[1][n] : qsel1;
    }
    const float qn_own = pg ? qsel1 : qsel0;
    float rsel0 = rdv[0][0], rsel1 = rdv[1][0];
#pragma unroll
    for (int n = 1; n < Nn - 1; ++n) {
        rsel0 = (gi == n) ? rdv[0][n] : rsel0;
        rsel1 = (gi == n) ? rdv[1][n] : rsel1;
    }
    const float rd_own = pg ? rsel1 : rsel0;

    // --- per-segment projection, one transcendental pass for both bf ---
    const float vn = fsqrtf_(fmaxf(qn_own, EPSF * EPSF));
    const float th = ftanh_pos(vn);
    float s_own = th * frcp(vn);
    float nrm = th;
    if (nrm > MAXNF) { s_own *= MAXNF * frcp(nrm); nrm = MAXNF; }
    const float zn2_own = nrm * nrm;

    // --- logmap step j at lane (16p + j), j = 1..13, one pass ---
    const float s_prev   = __shfl(s_own,   lane - 1, 64);
    const float zn2_prev = __shfl(zn2_own, lane - 1, 64);
    const float rd_prev  = __shfl(rd_own,  lane - 1, 64);   // rd[j-1] at lane j

    const float xyv  = -(s_prev * s_own * rd_prev);
    const float x2v  = zn2_prev, yy2 = zn2_own;
    const float c1v  = 1.f + 2.f * xyv + yy2;
    const float c2v  = 1.f - x2v;
    const float rdenv = frcp(fmaxf(1.f + 2.f * xyv + x2v * yy2, EPSF));
    const float un2 = rdenv * rdenv *
        (c1v * c1v * x2v + 2.f * c1v * c2v * xyv + c2v * c2v * yy2);
    const float un  = fsqrtf_(fmaxf(un2, EPSF * EPSF));
    const float lf  = fmaxf(1.f - x2v, EPSF);               // 2/lam
    const float gml = lf * fatanh01(fminf(un, MAXNF)) * frcp(un);
    const float wj  = WNORM * __expf(LN09 * (float)(13 - gi));  // 0.9^(13-j)
    const float gw  = wj * gml * rdenv;
    const float g1_own = -gw * c1v * s_prev;   // contribution to coef[j-1]
    const float g2_own =  gw * c2v * s_own;    // contribution to coef[j]

    // --- v_init for both bf (packed dims) ---
    v2f vi0v = vsplat(0.f), vi1v = vsplat(0.f);
#pragma unroll
    for (int n = 0; n < Nn; ++n) {
        float cf0 = 0.f, cf1 = 0.f;
        if (n >= 1)      { cf0 = __shfl(g2_own, n, 64);       cf1 = __shfl(g2_own, 16 + n, 64); }
        if (n <= Nn - 2) { cf0 += __shfl(g1_own, n + 1, 64);  cf1 += __shfl(g1_own, 17 + n, 64); }
        vi0v = vfmas(cf0, y0v[n], vi0v);
        vi1v = vfmas(cf1, y1v[n], vi1v);
    }
    const float scl0 = __shfl(s_own, 13, 64),  x2l0 = __shfl(zn2_own, 13, 64);
    const float scl1 = __shfl(s_own, 29, 64),  x2l1 = __shfl(zn2_own, 29, 64);
    const v2f z0lv = y0v[Nn-1] * scl0;   // z_last bf0 (2 dims)
    const v2f z1lv = y1v[Nn-1] * scl1;   // z_last bf1

    // --- logmap0(v_init) -> bcu (wave-private slab; no barrier needed) ---
    float vin20 = fmaf(vi0v.y, vi0v.y, vi0v.x * vi0v.x);
    float vin21 = fmaf(vi1v.y, vi1v.y, vi1v.x * vi1v.x);
#pragma unroll 1
    for (int off = 1; off < 64; off <<= 1) {
        vin20 += __shfl_xor(vin20, off, 64);
        vin21 += __shfl_xor(vin21, off, 64);
    }
    const float vinn0 = fsqrtf_(fmaxf(vin20, EPSF * EPSF));
    const float lgv0  = fatanh01(fminf(vinn0, MAXNF)) * frcp(vinn0);
    const float vinn1 = fsqrtf_(fmaxf(vin21, EPSF * EPSF));
    const float lgv1  = fatanh01(fminf(vinn1, MAXNF)) * frcp(vinn1);
    *reinterpret_cast<v2f*>(&bcu[(0 * 4 + c) * Dd + 2 * lane]) = vi0v * lgv0;
    *reinterpret_cast<v2f*>(&bcu[(4 + c) * Dd + 2 * lane])     = vi1v * lgv1;
    // same-wave DS ordering + compiler lgkmcnt handles write->read below.

    // --- vel matmul: weight loads shared across both bf, packed dims ---
    v2f m0v = bvv, m1v = bvv;
    {
        const float4* bc40 = reinterpret_cast<const float4*>(bcu + (0 * 4 + c) * Dd);
        const float4* bc41 = reinterpret_cast<const float4*>(bcu + (4 + c) * Dd);
#pragma unroll 1
        for (int kb = 0; kb < Dd / 8; ++kb) {      // 8-deep load batches
            v2f w[8];
#pragma unroll
            for (int r = 0; r < 8; ++r)
                w[r] = *reinterpret_cast<const v2f*>(Wvp + (8 * kb + r) * Dd);
            const float4 ta0 = bc40[2*kb], tb0 = bc40[2*kb+1];
            const float4 ta1 = bc41[2*kb], tb1 = bc41[2*kb+1];
            m0v = vfmas(ta0.x, w[0], m0v); m1v = vfmas(ta1.x, w[0], m1v);
            m0v = vfmas(ta0.y, w[1], m0v); m1v = vfmas(ta1.y, w[1], m1v);
            m0v = vfmas(ta0.z, w[2], m0v); m1v = vfmas(ta1.z, w[2], m1v);
            m0v = vfmas(ta0.w, w[3], m0v); m1v = vfmas(ta1.w, w[3], m1v);
            m0v = vfmas(tb0.x, w[4], m0v); m1v = vfmas(tb1.x, w[4], m1v);
            m0v = vfmas(tb0.y, w[5], m0v); m1v = vfmas(tb1.y, w[5], m1v);
            m0v = vfmas(tb0.z, w[6], m0v); m1v = vfmas(tb1.z, w[6], m1v);
            m0v = vfmas(tb0.w, w[7], m0v); m1v = vfmas(tb1.w, w[7], m1v);
        }
    }
    float mn20 = fmaf(m0v.y, m0v.y, m0v.x * m0v.x);
    float zdm0 = fmaf(z0lv.y, m0v.y, z0lv.x * m0v.x);
    float mn21 = fmaf(m1v.y, m1v.y, m1v.x * m1v.x);
    float zdm1 = fmaf(z1lv.y, m1v.y, z1lv.x * m1v.x);
#pragma unroll 1
    for (int off = 1; off < 64; off <<= 1) {
        mn20 += __shfl_xor(mn20, off, 64); zdm0 += __shfl_xor(zdm0, off, 64);
        mn21 += __shfl_xor(mn21, off, 64); zdm1 += __shfl_xor(zdm1, off, 64);
    }

    // --- expmap0 of velocity + horizon scalars, lane-parallel over (p, t) ---
    const float sig = frcp(1.f + __expf(-steps[c]));
    {
        const float mn2g = pg ? mn21 : mn20;
        const float zdmg = pg ? zdm1 : zdm0;
        const float x2lg = pg ? x2l1 : x2l0;
        const float mng  = fsqrtf_(fmaxf(mn2g, EPSF * EPSF));
        const float thg  = ftanh_pos(mng);
        float sc2g = thg * frcp(mng);
        float v0ng = thg;
        if (v0ng > MAXNF) { sc2g *= MAXNF * frcp(v0ng); v0ng = MAXNF; }
        const float v0n2g  = mn2g * sc2g * sc2g;
        const float zdotvg = sc2g * zdmg;
        const float lamxg  = 2.f * frcp(fmaxf(1.f - x2lg, EPSF));

        const float alpha = sig * (float)(gi + 1);
        const float vtn2  = alpha * alpha * v0n2g;
        const float vtn   = fsqrtf_(fmaxf(vtn2, EPSF * EPSF));
        const float gg    = ftanh_pos(0.5f * lamxg * vtn);
        const float cyc   = gg * alpha * frcp(vtn);
        const float y2    = cyc * cyc * v0n2g;
        const float xy    = cyc * zdotvg;
        const float c1 = 1.f + 2.f * xy + y2;
        const float c2 = 1.f - x2lg;
        const float rden = frcp(fmaxf(1.f + 2.f * xy + x2lg * y2, EPSF));
        float rn2 = rden * rden *
            (c1 * c1 * x2lg + 2.f * c1 * c2 * xy + c2 * c2 * y2);
        float rn = fsqrtf_(fmaxf(rn2, EPSF * EPSF));
        float sclip = 1.f;
        if (rn > MAXNF) { sclip = MAXNF * frcp(rn); rn = MAXNF; }
        const float At_own = c1 * rden * sclip;         // coeff of z_last
        const float Bt_own = c2 * cyc * rden * sclip;   // coeff of v0t
        if (lane < 32 && gi < Tt) zfns[pg][c][gi] = rn;

        const float sc2_0 = __shfl(sc2g, 0, 64), sc2_1 = __shfl(sc2g, 16, 64);
        const v2f v0d0 = m0v * sc2_0;   // v0t bf0
        const v2f v0d1 = m1v * sc2_1;   // v0t bf1
        // zfl writes land in the wave's OWN slab (aliases its dead xs; every
        // written value data-depends on all xs reads, so ordering is safe).
#pragma unroll 1
        for (int t = 0; t < Tt; ++t) {
            const float A0 = __shfl(At_own, t, 64),      B0 = __shfl(Bt_own, t, 64);
            const float A1 = __shfl(At_own, 16 + t, 64), B1 = __shfl(Bt_own, 16 + t, 64);
            *reinterpret_cast<v2f*>(ZFL2(c, 0, t) + 2 * lane) = vfmas(A0, z0lv, v0d0 * B0);
            *reinterpret_cast<v2f*>(ZFL2(c, 1, t) + 2 * lane) = vfmas(A1, z1lv, v0d1 * B1);
        }
    }
    __syncthreads();                                            // B4: first x-wave handoff

    // ======= Mobius fusion via Gram matrices: wave wid = horizon t, both bf =======
    {
        float mwa = mobius_w[0], mwb = mobius_w[1], mwc = mobius_w[2], mwd = mobius_w[3];
        const float mx = fmaxf(fmaxf(mwa, mwb), fmaxf(mwc, mwd));
        mwa = __expf(mwa - mx); mwb = __expf(mwb - mx);
        mwc = __expf(mwc - mx); mwd = __expf(mwd - mx);
        const float rse = frcp(mwa + mwb + mwc + mwd);
        const float mw[4] = {mwa * rse, mwb * rse, mwc * rse, mwd * rse};

        const int t = wid;
        v2f e0[4], e1[4];
#pragma unroll
        for (int i = 0; i < 4; ++i) {
            e0[i] = *reinterpret_cast<const v2f*>(ZFL2(i, 0, t) + 2 * lane);
            e1[i] = *reinterpret_cast<const v2f*>(ZFL2(i, 1, t) + 2 * lane);
        }
        float gp[12];
        gp[0]  = fmaf(e0[0].y, e0[1].y, e0[0].x * e0[1].x);
        gp[1]  = fmaf(e0[0].y, e0[2].y, e0[0].x * e0[2].x);
        gp[2]  = fmaf(e0[0].y, e0[3].y, e0[0].x * e0[3].x);
        gp[3]  = fmaf(e0[1].y, e0[2].y, e0[1].x * e0[2].x);
        gp[4]  = fmaf(e0[1].y, e0[3].y, e0[1].x * e0[3].x);
        gp[5]  = fmaf(e0[2].y, e0[3].y, e0[2].x * e0[3].x);
        gp[6]  = fmaf(e1[0].y, e1[1].y, e1[0].x * e1[1].x);
        gp[7]  = fmaf(e1[0].y, e1[2].y, e1[0].x * e1[2].x);
        gp[8]  = fmaf(e1[0].y, e1[3].y, e1[0].x * e1[3].x);
        gp[9]  = fmaf(e1[1].y, e1[2].y, e1[1].x * e1[2].x);
        gp[10] = fmaf(e1[1].y, e1[3].y, e1[1].x * e1[3].x);
        gp[11] = fmaf(e1[2].y, e1[3].y, e1[2].x * e1[3].x);
#pragma unroll 1
        for (int off = 1; off < 64; off <<= 1) {
#pragma unroll
            for (int k = 0; k < 12; ++k) gp[k] += __shfl_xor(gp[k], off, 64);
        }

        // mob_smul scales: one transcendental pass for 8 (p,i) at lanes 0-3,16-19
        const int il = lane & 3;
        float mwv_own = mw[0];
        mwv_own = (il == 1) ? mw[1] : mwv_own;
        mwv_own = (il == 2) ? mw[2] : mwv_own;
        mwv_own = (il == 3) ? mw[3] : mwv_own;
        const float xn_own = zfns[pg][il][t];
        const float smc = ftanh_pos(mwv_own * fatanh01(xn_own)) * frcp(xn_own);
        float smv[2][4];
#pragma unroll
        for (int i = 0; i < 4; ++i) {
            smv[0][i] = __shfl(smc, i, 64);
            smv[1][i] = __shfl(smc, 16 + i, 64);
        }

#pragma unroll
        for (int p = 0; p < 2; ++p) {
            const float xn0 = zfns[p][0][t], xn1 = zfns[p][1][t];
            const float xn2 = zfns[p][2][t], xn3 = zfns[p][3][t];
            const float Gd[4] = {xn0*xn0, xn1*xn1, xn2*xn2, xn3*xn3};
            const float G[4][4] = {
                {Gd[0], gp[6*p+0], gp[6*p+1], gp[6*p+2]},
                {gp[6*p+0], Gd[1], gp[6*p+3], gp[6*p+4]},
                {gp[6*p+1], gp[6*p+3], Gd[2], gp[6*p+5]},
                {gp[6*p+2], gp[6*p+4], gp[6*p+5], Gd[3]}};
            float a0 = smv[p][0], a1 = 0.f, a2 = 0.f, a3 = 0.f;
            float cn2 = smv[p][0] * smv[p][0] * Gd[0];
#pragma unroll
            for (int i = 1; i < 4; ++i) {
                const float si = smv[p][i];
                const float xy = si * (a0*G[0][i] + a1*G[1][i] + a2*G[2][i] + a3*G[3][i]);
                const float y2 = si * si * Gd[i];
                const float c1 = 1.f + 2.f * xy + y2;
                const float c2 = 1.f - cn2;
                const float rden = frcp(fmaxf(1.f + 2.f * xy + cn2 * y2, EPSF));
                const float f1 = rden * c1, f2 = rden * c2 * si;
                a0 *= f1; a1 *= f1; a2 *= f1; a3 *= f1;
                if (i == 1) a1 += f2; else if (i == 2) a2 += f2; else a3 += f2;
                cn2 = rden * rden * (c1*c1*cn2 + 2.f*c1*c2*xy + c2*c2*y2);
            }
            float cn = fsqrtf_(fmaxf(cn2, EPSF * EPSF));
            float csc = 1.f;
            if (cn > MAXNF) { csc = MAXNF * frcp(cn); cn = MAXNF; }
            const float lg = fatanh01(cn) * frcp(cn) * csc;
            const v2f* ee = p ? e1 : e0;
            v2f uv = ee[0] * a0;
            uv = vfmas(a1, ee[1], uv);
            uv = vfmas(a2, ee[2], uv);
            uv = vfmas(a3, ee[3], uv);
            uv = uv * lg;
            // uls2 layout: [t][Dd][p] -> index (t*Dd + d)*2 + p (in bcu)
            const int ub = (t * Dd + 2 * lane) * 2 + p;
            bcu[ub]     = uv.x;
            bcu[ub + 2] = uv.y;
        }
    }

    // ---- hinge-loss partials: wave 0, lanes 0-15 bf0, 16-31 bf1 ----
    if (wid == 0) {
        float ddv = 0.f;
        if (lane < 32)
            ddv = 2.f * fatanh01(zfns[pg][lane & 3][gi >> 2]);
        const float ddn = __shfl(ddv, lane + 1, 64);
        float hv = ((lane < 32) && ((lane & 3) != 3))
                 ? fmaxf(ddv - ddn + 0.1f, 0.f) : 0.f;
#pragma unroll 1
        for (int off = 1; off < 16; off <<= 1) hv += __shfl_xor(hv, off, 64);
        if (lane == 0)  hpart[bf0]     = hv;
        if (lane == 16) hpart[bf0 + 1] = hv;
    }
    __syncthreads();                                            // B5 (zfl dead)

    // ---- reconstruction hidden layer: thread tid = hidden j, p-packed ----
    {
        const float4* u4 = reinterpret_cast<const float4*>(bcu);   // [t][k-pairs][p]
        const float bb = rec_b1[tid];
        v2f accv[4] = {vsplat(bb), vsplat(bb), vsplat(bb), vsplat(bb)};
        const float* w1p = rec_W1 + tid;
#pragma unroll 1
        for (int kb = 0; kb < Dd / 8; ++kb) {      // 8-deep weight load batches
            float wv[8];
#pragma unroll
            for (int r = 0; r < 8; ++r) wv[r] = w1p[(8 * kb + r) * Hh];
#pragma unroll
            for (int rr = 0; rr < 4; ++rr) {       // k-pairs (8kb+2rr, 8kb+2rr+1)
#pragma unroll
                for (int t = 0; t < 4; ++t) {
                    const float4 U = u4[t * (Dd / 2) + 4 * kb + rr];
                    accv[t] = vfmas(wv[2*rr],   vset(U.x, U.y), accv[t]);
                    accv[t] = vfmas(wv[2*rr+1], vset(U.z, U.w), accv[t]);
                }
            }
        }
        // hbuf2 layout: [t][Hh][p] in lds_big
#pragma unroll
        for (int t = 0; t < 4; ++t) {
            v2f h = vset(fmaxf(accv[t].x, 0.f), fmaxf(accv[t].y, 0.f));
            *reinterpret_cast<v2f*>(lds_big + (t * Hh + tid) * 2) = h;
        }
    }
    __syncthreads();                                            // B6

    // ---- seg outputs: 96 threads, each handles (t,s) for BOTH bf ----
    if (tid < Tt * SEGc) {
        const int t = tid / SEGc, s = tid - t * SEGc;
        const float4* h4 = reinterpret_cast<const float4*>(lds_big);  // [t][j-pairs][p]
        const float* w2p = rec_W2 + s;
        v2f acc2 = vsplat(rec_b2[s]);
#pragma unroll 1
        for (int jb = 0; jb < Hh / 8; ++jb) {
            float wv[8];
#pragma unroll
            for (int r = 0; r < 8; ++r) wv[r] = w2p[(8 * jb + r) * SEGc];
#pragma unroll
            for (int rr = 0; rr < 4; ++rr) {       // j-pairs (8jb+2rr, 8jb+2rr+1)
                const float4 H = h4[t * (Hh / 2) + 4 * jb + rr];
                acc2 = vfmas(wv[2*rr],   vset(H.x, H.y), acc2);
                acc2 = vfmas(wv[2*rr+1], vset(H.z, H.w), acc2);
            }
        }
        const v2f rbv = vset(rb0v, rb1v);
        const v2f rwr = vset(frcp(rw0v), frcp(rw1v));
        const v2f sdv = vset(stdv0, stdv1);
        const v2f mnv = vset(mean0, mean1);
        const v2f res = (acc2 - rbv) * rwr * sdv + mnv;   // RevIN denorm
        *reinterpret_cast<float2*>(&out[(b * (Tt * SEGc) + tid) * Ff + f0]) =
            make_float2(res.x, res.y);
    }
#undef XSW
#undef ZFL2
}

// ---------------- deterministic hloss reduction ----------------
__global__ __launch_bounds__(256) void hloss_kernel(
    const float* __restrict__ hpart, float* __restrict__ out)
{
    __shared__ float sm[256];
    const int tid = threadIdx.x;
    float s = 0.f;
#pragma unroll 1
    for (int i = tid; i < BFc; i += 256) s += hpart[i];
    sm[tid] = s;
    __syncthreads();
#pragma unroll 1
    for (int off = 128; off > 0; off >>= 1) {
        if (tid < off) sm[tid] += sm[tid + off];
        __syncthreads();
    }
    if (tid == 0) out[Bb * Tt * SEGc * Ff] = sm[0] / (float)(BFc * Tt);
}

extern "C" void kernel_launch(void* const* d_in, const int* in_sizes, int n_in,
                              void* d_out, int out_size, void* d_ws, size_t ws_size,
                              hipStream_t stream) {
    const float* trend   = (const float*)d_in[0];
    const float* scoarse = (const float*)d_in[1];
    const float* sfine   = (const float*)d_in[2];
    const float* resid   = (const float*)d_in[3];
    const float* revin_w = (const float*)d_in[4];
    const float* revin_b = (const float*)d_in[5];
    const float* enc_W   = (const float*)d_in[6];
    const float* enc_b   = (const float*)d_in[7];
    const float* vel_W   = (const float*)d_in[8];
    const float* vel_b   = (const float*)d_in[9];
    const float* steps   = (const float*)d_in[10];
    const float* mobw    = (const float*)d_in[11];
    const float* rec_W1  = (const float*)d_in[12];
    const float* rec_b1  = (const float*)d_in[13];
    const float* rec_W2  = (const float*)d_in[14];
    const float* rec_b2  = (const float*)d_in[15];

    float* out = (float*)d_out;
    float* wsf = (float*)d_ws;           // hpart[8192]

    fused_kernel<<<BFc / 2, 256, 0, stream>>>(
        trend, scoarse, sfine, resid, revin_w, revin_b,
        enc_W, enc_b, vel_W, vel_b, steps, mobw,
        rec_W1, rec_b1, rec_W2, rec_b2,
        out, wsf);
    hloss_kernel<<<1, 256, 0, stream>>>(wsf, out);
}

// Round 12
// 234.741 us; speedup vs baseline: 1.0143x; 1.0143x over previous
//
#include <hip/hip_runtime.h>
#include <math.h>

#define EPSF 1e-5f
#define MAXNF (1.0f - 1e-5f)

constexpr int SEGc = 24;
constexpr int Nn   = 14;          // L / SEG
constexpr int NS   = Nn * SEGc;   // 336
constexpr int Tt   = 4;           // horizons
constexpr int Bb   = 32;
constexpr int Ll   = 336;
constexpr int Ff   = 256;
constexpr int Dd   = 128;
constexpr int Hh   = 256;
constexpr int BFc  = Bb * Ff;     // 8192

// v_init weight norm: 1 / (sum_{i=0}^{12} 0.9^i * 13)
constexpr float WNORM = 1.0f / (7.458134171670999f * 13.0f);
constexpr float LN09  = -0.10536051565782628f;   // ln(0.9)

// ---- packed fp32 (v_pk_fma_f32 on gfx90a+) ----
typedef float v2f __attribute__((ext_vector_type(2)));
__device__ __forceinline__ v2f vset(float a, float b){ v2f r; r.x=a; r.y=b; return r; }
__device__ __forceinline__ v2f vsplat(float s){ v2f r; r.x=s; r.y=s; return r; }
__device__ __forceinline__ v2f vfma(v2f a, v2f b, v2f c){
#if __has_builtin(__builtin_elementwise_fma)
    return __builtin_elementwise_fma(a, b, c);
#else
    return vset(fmaf(a.x, b.x, c.x), fmaf(a.y, b.y, c.y));
#endif
}
__device__ __forceinline__ v2f vfmas(float a, v2f b, v2f c){ return vfma(vsplat(a), b, c); }

// ---- fast math (tolerance 1.8e-2; these are ~1e-7 relative) ----
__device__ __forceinline__ float frcp(float x)  { return __builtin_amdgcn_rcpf(x); }
__device__ __forceinline__ float fsqrtf_(float x){ return __builtin_amdgcn_sqrtf(x); }
__device__ __forceinline__ float ftanh_pos(float x) {       // x >= 0
    const float e = __expf(fminf(2.f * x, 30.f));           // v_exp_f32
    return (e - 1.f) * frcp(e + 1.f);
}
__device__ __forceinline__ float fatanh01(float x) {        // 0 <= x <= MAXNF
    return 0.5f * __logf((1.f + x) * frcp(1.f - x));        // v_log_f32
}

// ---------------- fused kernel: one block (4 waves) per bf PAIR ----------------
// R10 structure (best measured: 253 us dispatch). ONLY change this round:
// the three weight-matmul loops (vel, rec_W1, rec_W2) are explicitly
// software-pipelined with ping-pong register batches (wA/wB), so batch k+1's
// global loads are in flight while batch k's FMAs execute. The rolled
// (unroll 1) loops serialized load->use, exposing a full L2 round-trip
// (~200-400 cy under contention) per 8-load batch x 64 batches/wave.
__global__ __launch_bounds__(256, 4) void fused_kernel(
    const float* __restrict__ trend, const float* __restrict__ scoarse,
    const float* __restrict__ sfine, const float* __restrict__ resid,
    const float* __restrict__ revin_w, const float* __restrict__ revin_b,
    const float* __restrict__ enc_W, const float* __restrict__ enc_b,
    const float* __restrict__ vel_W, const float* __restrict__ vel_b,
    const float* __restrict__ steps, const float* __restrict__ mobius_w,
    const float* __restrict__ rec_W1, const float* __restrict__ rec_b1,
    const float* __restrict__ rec_W2, const float* __restrict__ rec_b2,
    float* __restrict__ out, float* __restrict__ hpart)
{
    // XCD-chunking swizzle over 4096 pair-blocks (8 XCDs x 512 chunk).
    const int bid   = blockIdx.x;
    const int kpair = ((bid & 7) << 9) | (bid >> 3);   // 0..4095
    const int bf0   = kpair << 1;
    const int b     = bf0 >> 8;
    const int f0    = bf0 & 255;          // even
    const int tid   = threadIdx.x;
    const int wid   = tid >> 6;           // 0..3 = component
    const int lane  = tid & 63;
    const int gi    = lane & 15;          // item index within group
    const int pg    = (lane >> 4) & 1;    // group p (meaningful for lanes 0..31)

    __shared__ float lds_big[2 * 4 * Tt * Dd];   // 4096 floats = 16 KB, time-shared
    __shared__ float bcu[8 * Dd];                // [p][c]Dd bc; later uls2 [t][Dd][p]
    __shared__ float zfns[2][4][Tt];             // clipped norms per p
    __shared__ float red[16];

#define XS(p, c)     (lds_big + ((p) * 4 + (c)) * NS)                 // 8*336 floats
#define ZFL(p, i, t) (lds_big + (((p) * 4 + (i)) * Tt + (t)) * Dd)    // 4096 floats

    const float* cp = (wid == 0) ? trend : (wid == 1) ? scoarse
                    : (wid == 2) ? sfine : resid;

    // ---- stage raw rows: one float2 load serves both bf ----
#pragma unroll 1
    for (int i = lane; i < NS; i += 64) {
        const float2 v = *reinterpret_cast<const float2*>(&cp[(b * Ll + i) * Ff + f0]);
        XS(0, wid)[i] = v.x;
        XS(1, wid)[i] = v.y;
    }
    __syncthreads();                                            // B1

    // ---- RevIN stats for both bf ----
    float s0 = 0.f, q0 = 0.f, s1 = 0.f, q1 = 0.f;
#pragma unroll 1
    for (int l = tid; l < NS; l += 256) {
        const float x0 = XS(0,0)[l] + XS(0,1)[l] + XS(0,2)[l] + XS(0,3)[l];
        const float x1 = XS(1,0)[l] + XS(1,1)[l] + XS(1,2)[l] + XS(1,3)[l];
        s0 += x0; q0 += x0 * x0; s1 += x1; q1 += x1 * x1;
    }
#pragma unroll 1
    for (int off = 1; off < 64; off <<= 1) {
        s0 += __shfl_xor(s0, off, 64); q0 += __shfl_xor(q0, off, 64);
        s1 += __shfl_xor(s1, off, 64); q1 += __shfl_xor(q1, off, 64);
    }
    if (lane == 0) {
        red[wid] = s0; red[4 + wid] = q0; red[8 + wid] = s1; red[12 + wid] = q1;
    }
    __syncthreads();                                            // B2
    s0 = red[0] + red[1] + red[2] + red[3];
    q0 = red[4] + red[5] + red[6] + red[7];
    s1 = red[8] + red[9] + red[10] + red[11];
    q1 = red[12] + red[13] + red[14] + red[15];
    const float mean0 = s0 * (1.f / (float)NS);
    const float stdv0 = fsqrtf_(q0 * (1.f / (float)NS) - mean0 * mean0 + 1e-5f);
    const float mean1 = s1 * (1.f / (float)NS);
    const float stdv1 = fsqrtf_(q1 * (1.f / (float)NS) - mean1 * mean1 + 1e-5f);
    const float rw0v = revin_w[f0],     rb0v = revin_b[f0];
    const float rw1v = revin_w[f0 + 1], rb1v = revin_b[f0 + 1];
    const float aff0 = frcp(stdv0) * rw0v;
    const float kaf0 = 0.25f * (rb0v - mean0 * aff0);
    const float aff1 = frcp(stdv1) * rw1v;
    const float kaf1 = 0.25f * (rb1v - mean1 * aff1);

    // ================= branch (component c = wid, both bf) =================
    const int c = wid;
    const float4* xv40 = reinterpret_cast<const float4*>(XS(0, c));
    const float4* xv41 = reinterpret_cast<const float4*>(XS(1, c));
    const float* Wep = enc_W + c * SEGc * Dd + 2 * lane;
    const float* Wvp = vel_W + c * Dd * Dd + 2 * lane;

    v2f wreg[SEGc];
#pragma unroll
    for (int s = 0; s < SEGc; ++s)
        wreg[s] = *reinterpret_cast<const v2f*>(Wep + s * Dd);
    const v2f bev = *reinterpret_cast<const v2f*>(enc_b + c * Dd + 2 * lane);
    const v2f bvv = *reinterpret_cast<const v2f*>(vel_b + c * Dd + 2 * lane);

    v2f csv = vsplat(0.f);
#pragma unroll
    for (int s = 0; s < SEGc; ++s) csv += wreg[s];
    const v2f kb0v = vfmas(kaf0, csv, bev);
    const v2f kb1v = vfmas(kaf1, csv, bev);

    // --- Phase A: 28 encoder dots (14 per bf), packed dims ---
    v2f y0v[Nn], y1v[Nn];
#pragma unroll
    for (int n = 0; n < Nn; ++n) {
        v2f a0 = vsplat(0.f), a1 = vsplat(0.f);
#pragma unroll
        for (int q = 0; q < SEGc / 4; ++q) {
            const float4 xa = xv40[n * (SEGc / 4) + q];
            const float4 xb = xv41[n * (SEGc / 4) + q];
            a0 = vfmas(xa.x, wreg[4*q+0], a0); a1 = vfmas(xb.x, wreg[4*q+0], a1);
            a0 = vfmas(xa.y, wreg[4*q+1], a0); a1 = vfmas(xb.y, wreg[4*q+1], a1);
            a0 = vfmas(xa.z, wreg[4*q+2], a0); a1 = vfmas(xb.z, wreg[4*q+2], a1);
            a0 = vfmas(xa.w, wreg[4*q+3], a0); a1 = vfmas(xb.w, wreg[4*q+3], a1);
        }
        y0v[n] = vfmas(aff0, a0, kb0v);
        y1v[n] = vfmas(aff1, a1, kb1v);
    }

    // --- |y_n|^2 and neighbor dots for both bf: ONE rolled butterfly (54 vals) ---
    float qnv[2][Nn], rdv[2][Nn - 1];
#pragma unroll
    for (int n = 0; n < Nn; ++n) {
        qnv[0][n] = fmaf(y0v[n].y, y0v[n].y, y0v[n].x * y0v[n].x);
        qnv[1][n] = fmaf(y1v[n].y, y1v[n].y, y1v[n].x * y1v[n].x);
    }
#pragma unroll
    for (int n = 1; n < Nn; ++n) {
        rdv[0][n - 1] = fmaf(y0v[n-1].y, y0v[n].y, y0v[n-1].x * y0v[n].x);
        rdv[1][n - 1] = fmaf(y1v[n-1].y, y1v[n].y, y1v[n-1].x * y1v[n].x);
    }
#pragma unroll 1
    for (int off = 1; off < 64; off <<= 1) {
#pragma unroll
        for (int n = 0; n < Nn; ++n) {
            qnv[0][n] += __shfl_xor(qnv[0][n], off, 64);
            qnv[1][n] += __shfl_xor(qnv[1][n], off, 64);
        }
#pragma unroll
        for (int j = 0; j < Nn - 1; ++j) {
            rdv[0][j] += __shfl_xor(rdv[0][j], off, 64);
            rdv[1][j] += __shfl_xor(rdv[1][j], off, 64);
        }
    }
    float qsel0 = qnv[0][0], qsel1 = qnv[1][0];
#pragma unroll
    for (int n = 1; n < Nn; ++n) {
        qsel0 = (gi == n) ? qnv[0][n] : qsel0;
        qsel1 = (gi == n) ? qnv[1][n] : qsel1;
    }
    const float qn_own = pg ? qsel1 : qsel0;
    float rsel0 = rdv[0][0], rsel1 = rdv[1][0];
#pragma unroll
    for (int n = 1; n < Nn - 1; ++n) {
        rsel0 = (gi == n) ? rdv[0][n] : rsel0;
        rsel1 = (gi == n) ? rdv[1][n] : rsel1;
    }
    const float rd_own = pg ? rsel1 : rsel0;

    // --- per-segment projection, one transcendental pass for both bf ---
    const float vn = fsqrtf_(fmaxf(qn_own, EPSF * EPSF));
    const float th = ftanh_pos(vn);
    float s_own = th * frcp(vn);
    float nrm = th;
    if (nrm > MAXNF) { s_own *= MAXNF * frcp(nrm); nrm = MAXNF; }
    const float zn2_own = nrm * nrm;

    // --- logmap step j at lane (16p + j), j = 1..13, one pass ---
    const float s_prev   = __shfl(s_own,   lane - 1, 64);
    const float zn2_prev = __shfl(zn2_own, lane - 1, 64);
    const float rd_prev  = __shfl(rd_own,  lane - 1, 64);   // rd[j-1] at lane j

    const float xyv  = -(s_prev * s_own * rd_prev);
    const float x2v  = zn2_prev, yy2 = zn2_own;
    const float c1v  = 1.f + 2.f * xyv + yy2;
    const float c2v  = 1.f - x2v;
    const float rdenv = frcp(fmaxf(1.f + 2.f * xyv + x2v * yy2, EPSF));
    const float un2 = rdenv * rdenv *
        (c1v * c1v * x2v + 2.f * c1v * c2v * xyv + c2v * c2v * yy2);
    const float un  = fsqrtf_(fmaxf(un2, EPSF * EPSF));
    const float lf  = fmaxf(1.f - x2v, EPSF);               // 2/lam
    const float gml = lf * fatanh01(fminf(un, MAXNF)) * frcp(un);
    const float wj  = WNORM * __expf(LN09 * (float)(13 - gi));  // 0.9^(13-j)
    const float gw  = wj * gml * rdenv;
    const float g1_own = -gw * c1v * s_prev;   // contribution to coef[j-1]
    const float g2_own =  gw * c2v * s_own;    // contribution to coef[j]

    // --- v_init for both bf (packed dims) ---
    v2f vi0v = vsplat(0.f), vi1v = vsplat(0.f);
#pragma unroll
    for (int n = 0; n < Nn; ++n) {
        float cf0 = 0.f, cf1 = 0.f;
        if (n >= 1)      { cf0 = __shfl(g2_own, n, 64);       cf1 = __shfl(g2_own, 16 + n, 64); }
        if (n <= Nn - 2) { cf0 += __shfl(g1_own, n + 1, 64);  cf1 += __shfl(g1_own, 17 + n, 64); }
        vi0v = vfmas(cf0, y0v[n], vi0v);
        vi1v = vfmas(cf1, y1v[n], vi1v);
    }
    const float scl0 = __shfl(s_own, 13, 64),  x2l0 = __shfl(zn2_own, 13, 64);
    const float scl1 = __shfl(s_own, 29, 64),  x2l1 = __shfl(zn2_own, 29, 64);
    const v2f z0lv = y0v[Nn-1] * scl0;   // z_last bf0 (2 dims)
    const v2f z1lv = y1v[Nn-1] * scl1;   // z_last bf1

    // --- logmap0(v_init) -> bcu ---
    float vin20 = fmaf(vi0v.y, vi0v.y, vi0v.x * vi0v.x);
    float vin21 = fmaf(vi1v.y, vi1v.y, vi1v.x * vi1v.x);
#pragma unroll 1
    for (int off = 1; off < 64; off <<= 1) {
        vin20 += __shfl_xor(vin20, off, 64);
        vin21 += __shfl_xor(vin21, off, 64);
    }
    const float vinn0 = fsqrtf_(fmaxf(vin20, EPSF * EPSF));
    const float lgv0  = fatanh01(fminf(vinn0, MAXNF)) * frcp(vinn0);
    const float vinn1 = fsqrtf_(fmaxf(vin21, EPSF * EPSF));
    const float lgv1  = fatanh01(fminf(vinn1, MAXNF)) * frcp(vinn1);
    *reinterpret_cast<v2f*>(&bcu[(0 * 4 + c) * Dd + 2 * lane]) = vi0v * lgv0;
    *reinterpret_cast<v2f*>(&bcu[(4 + c) * Dd + 2 * lane])     = vi1v * lgv1;
    __syncthreads();                                            // B3 (xs dead)

    // --- vel matmul: ping-pong software pipeline (batch k+1 in flight) ---
    v2f m0v = bvv, m1v = bvv;
    {
        const float4* bc40 = reinterpret_cast<const float4*>(bcu + (0 * 4 + c) * Dd);
        const float4* bc41 = reinterpret_cast<const float4*>(bcu + (4 + c) * Dd);
        v2f wA[8], wB[8];
#pragma unroll
        for (int r = 0; r < 8; ++r)
            wA[r] = *reinterpret_cast<const v2f*>(Wvp + r * Dd);

#define VCONS(W, KB) { \
        const float4 ta0 = bc40[2*(KB)], tb0 = bc40[2*(KB)+1]; \
        const float4 ta1 = bc41[2*(KB)], tb1 = bc41[2*(KB)+1]; \
        m0v = vfmas(ta0.x, W[0], m0v); m1v = vfmas(ta1.x, W[0], m1v); \
        m0v = vfmas(ta0.y, W[1], m0v); m1v = vfmas(ta1.y, W[1], m1v); \
        m0v = vfmas(ta0.z, W[2], m0v); m1v = vfmas(ta1.z, W[2], m1v); \
        m0v = vfmas(ta0.w, W[3], m0v); m1v = vfmas(ta1.w, W[3], m1v); \
        m0v = vfmas(tb0.x, W[4], m0v); m1v = vfmas(tb1.x, W[4], m1v); \
        m0v = vfmas(tb0.y, W[5], m0v); m1v = vfmas(tb1.y, W[5], m1v); \
        m0v = vfmas(tb0.z, W[6], m0v); m1v = vfmas(tb1.z, W[6], m1v); \
        m0v = vfmas(tb0.w, W[7], m0v); m1v = vfmas(tb1.w, W[7], m1v); }

#pragma unroll 1
        for (int kb = 0; kb < Dd / 8; kb += 2) {
#pragma unroll
            for (int r = 0; r < 8; ++r)
                wB[r] = *reinterpret_cast<const v2f*>(Wvp + ((kb + 1) * 8 + r) * Dd);
            VCONS(wA, kb)
            if (kb + 2 < Dd / 8) {
#pragma unroll
                for (int r = 0; r < 8; ++r)
                    wA[r] = *reinterpret_cast<const v2f*>(Wvp + ((kb + 2) * 8 + r) * Dd);
            }
            VCONS(wB, kb + 1)
        }
#undef VCONS
    }
    float mn20 = fmaf(m0v.y, m0v.y, m0v.x * m0v.x);
    float zdm0 = fmaf(z0lv.y, m0v.y, z0lv.x * m0v.x);
    float mn21 = fmaf(m1v.y, m1v.y, m1v.x * m1v.x);
    float zdm1 = fmaf(z1lv.y, m1v.y, z1lv.x * m1v.x);
#pragma unroll 1
    for (int off = 1; off < 64; off <<= 1) {
        mn20 += __shfl_xor(mn20, off, 64); zdm0 += __shfl_xor(zdm0, off, 64);
        mn21 += __shfl_xor(mn21, off, 64); zdm1 += __shfl_xor(zdm1, off, 64);
    }

    // --- expmap0 of velocity + horizon scalars, lane-parallel over (p, t) ---
    const float sig = frcp(1.f + __expf(-steps[c]));
    {
        const float mn2g = pg ? mn21 : mn20;
        const float zdmg = pg ? zdm1 : zdm0;
        const float x2lg = pg ? x2l1 : x2l0;
        const float mng  = fsqrtf_(fmaxf(mn2g, EPSF * EPSF));
        const float thg  = ftanh_pos(mng);
        float sc2g = thg * frcp(mng);
        float v0ng = thg;
        if (v0ng > MAXNF) { sc2g *= MAXNF * frcp(v0ng); v0ng = MAXNF; }
        const float v0n2g  = mn2g * sc2g * sc2g;
        const float zdotvg = sc2g * zdmg;
        const float lamxg  = 2.f * frcp(fmaxf(1.f - x2lg, EPSF));

        const float alpha = sig * (float)(gi + 1);
        const float vtn2  = alpha * alpha * v0n2g;
        const float vtn   = fsqrtf_(fmaxf(vtn2, EPSF * EPSF));
        const float gg    = ftanh_pos(0.5f * lamxg * vtn);
        const float cyc   = gg * alpha * frcp(vtn);
        const float y2    = cyc * cyc * v0n2g;
        const float xy    = cyc * zdotvg;
        const float c1 = 1.f + 2.f * xy + y2;
        const float c2 = 1.f - x2lg;
        const float rden = frcp(fmaxf(1.f + 2.f * xy + x2lg * y2, EPSF));
        float rn2 = rden * rden *
            (c1 * c1 * x2lg + 2.f * c1 * c2 * xy + c2 * c2 * y2);
        float rn = fsqrtf_(fmaxf(rn2, EPSF * EPSF));
        float sclip = 1.f;
        if (rn > MAXNF) { sclip = MAXNF * frcp(rn); rn = MAXNF; }
        const float At_own = c1 * rden * sclip;         // coeff of z_last
        const float Bt_own = c2 * cyc * rden * sclip;   // coeff of v0t
        if (lane < 32 && gi < Tt) zfns[pg][c][gi] = rn;

        const float sc2_0 = __shfl(sc2g, 0, 64), sc2_1 = __shfl(sc2g, 16, 64);
        const v2f v0d0 = m0v * sc2_0;   // v0t bf0
        const v2f v0d1 = m1v * sc2_1;   // v0t bf1
#pragma unroll 1
        for (int t = 0; t < Tt; ++t) {
            const float A0 = __shfl(At_own, t, 64),      B0 = __shfl(Bt_own, t, 64);
            const float A1 = __shfl(At_own, 16 + t, 64), B1 = __shfl(Bt_own, 16 + t, 64);
            *reinterpret_cast<v2f*>(ZFL(0, c, t) + 2 * lane) = vfmas(A0, z0lv, v0d0 * B0);
            *reinterpret_cast<v2f*>(ZFL(1, c, t) + 2 * lane) = vfmas(A1, z1lv, v0d1 * B1);
        }
    }
    __syncthreads();                                            // B4 (bc dead)

    // ======= Mobius fusion via Gram matrices: wave wid = horizon t, both bf =======
    {
        float mwa = mobius_w[0], mwb = mobius_w[1], mwc = mobius_w[2], mwd = mobius_w[3];
        const float mx = fmaxf(fmaxf(mwa, mwb), fmaxf(mwc, mwd));
        mwa = __expf(mwa - mx); mwb = __expf(mwb - mx);
        mwc = __expf(mwc - mx); mwd = __expf(mwd - mx);
        const float rse = frcp(mwa + mwb + mwc + mwd);
        const float mw[4] = {mwa * rse, mwb * rse, mwc * rse, mwd * rse};

        const int t = wid;
        v2f e0[4], e1[4];
#pragma unroll
        for (int i = 0; i < 4; ++i) {
            e0[i] = *reinterpret_cast<const v2f*>(ZFL(0, i, t) + 2 * lane);
            e1[i] = *reinterpret_cast<const v2f*>(ZFL(1, i, t) + 2 * lane);
        }
        float gp[12];
        gp[0]  = fmaf(e0[0].y, e0[1].y, e0[0].x * e0[1].x);
        gp[1]  = fmaf(e0[0].y, e0[2].y, e0[0].x * e0[2].x);
        gp[2]  = fmaf(e0[0].y, e0[3].y, e0[0].x * e0[3].x);
        gp[3]  = fmaf(e0[1].y, e0[2].y, e0[1].x * e0[2].x);
        gp[4]  = fmaf(e0[1].y, e0[3].y, e0[1].x * e0[3].x);
        gp[5]  = fmaf(e0[2].y, e0[3].y, e0[2].x * e0[3].x);
        gp[6]  = fmaf(e1[0].y, e1[1].y, e1[0].x * e1[1].x);
        gp[7]  = fmaf(e1[0].y, e1[2].y, e1[0].x * e1[2].x);
        gp[8]  = fmaf(e1[0].y, e1[3].y, e1[0].x * e1[3].x);
        gp[9]  = fmaf(e1[1].y, e1[2].y, e1[1].x * e1[2].x);
        gp[10] = fmaf(e1[1].y, e1[3].y, e1[1].x * e1[3].x);
        gp[11] = fmaf(e1[2].y, e1[3].y, e1[2].x * e1[3].x);
#pragma unroll 1
        for (int off = 1; off < 64; off <<= 1) {
#pragma unroll
            for (int k = 0; k < 12; ++k) gp[k] += __shfl_xor(gp[k], off, 64);
        }

        // mob_smul scales: one transcendental pass for 8 (p,i) at lanes 0-3,16-19
        const int il = lane & 3;
        float mwv_own = mw[0];
        mwv_own = (il == 1) ? mw[1] : mwv_own;
        mwv_own = (il == 2) ? mw[2] : mwv_own;
        mwv_own = (il == 3) ? mw[3] : mwv_own;
        const float xn_own = zfns[pg][il][t];
        const float smc = ftanh_pos(mwv_own * fatanh01(xn_own)) * frcp(xn_own);
        float smv[2][4];
#pragma unroll
        for (int i = 0; i < 4; ++i) {
            smv[0][i] = __shfl(smc, i, 64);
            smv[1][i] = __shfl(smc, 16 + i, 64);
        }

#pragma unroll
        for (int p = 0; p < 2; ++p) {
            const float xn0 = zfns[p][0][t], xn1 = zfns[p][1][t];
            const float xn2 = zfns[p][2][t], xn3 = zfns[p][3][t];
            const float Gd[4] = {xn0*xn0, xn1*xn1, xn2*xn2, xn3*xn3};
            const float G[4][4] = {
                {Gd[0], gp[6*p+0], gp[6*p+1], gp[6*p+2]},
                {gp[6*p+0], Gd[1], gp[6*p+3], gp[6*p+4]},
                {gp[6*p+1], gp[6*p+3], Gd[2], gp[6*p+5]},
                {gp[6*p+2], gp[6*p+4], gp[6*p+5], Gd[3]}};
            float a0 = smv[p][0], a1 = 0.f, a2 = 0.f, a3 = 0.f;
            float cn2 = smv[p][0] * smv[p][0] * Gd[0];
#pragma unroll
            for (int i = 1; i < 4; ++i) {
                const float si = smv[p][i];
                const float xy = si * (a0*G[0][i] + a1*G[1][i] + a2*G[2][i] + a3*G[3][i]);
                const float y2 = si * si * Gd[i];
                const float c1 = 1.f + 2.f * xy + y2;
                const float c2 = 1.f - cn2;
                const float rden = frcp(fmaxf(1.f + 2.f * xy + cn2 * y2, EPSF));
                const float f1 = rden * c1, f2 = rden * c2 * si;
                a0 *= f1; a1 *= f1; a2 *= f1; a3 *= f1;
                if (i == 1) a1 += f2; else if (i == 2) a2 += f2; else a3 += f2;
                cn2 = rden * rden * (c1*c1*cn2 + 2.f*c1*c2*xy + c2*c2*y2);
            }
            float cn = fsqrtf_(fmaxf(cn2, EPSF * EPSF));
            float csc = 1.f;
            if (cn > MAXNF) { csc = MAXNF * frcp(cn); cn = MAXNF; }
            const float lg = fatanh01(cn) * frcp(cn) * csc;
            const v2f* ee = p ? e1 : e0;
            v2f uv = ee[0] * a0;
            uv = vfmas(a1, ee[1], uv);
            uv = vfmas(a2, ee[2], uv);
            uv = vfmas(a3, ee[3], uv);
            uv = uv * lg;
            // uls2 layout: [t][Dd][p] -> index (t*Dd + d)*2 + p (in bcu)
            const int ub = (t * Dd + 2 * lane) * 2 + p;
            bcu[ub]     = uv.x;
            bcu[ub + 2] = uv.y;
        }
    }

    // ---- hinge-loss partials: wave 0, lanes 0-15 bf0, 16-31 bf1 ----
    if (wid == 0) {
        float ddv = 0.f;
        if (lane < 32)
            ddv = 2.f * fatanh01(zfns[pg][lane & 3][gi >> 2]);
        const float ddn = __shfl(ddv, lane + 1, 64);
        float hv = ((lane < 32) && ((lane & 3) != 3))
                 ? fmaxf(ddv - ddn + 0.1f, 0.f) : 0.f;
#pragma unroll 1
        for (int off = 1; off < 16; off <<= 1) hv += __shfl_xor(hv, off, 64);
        if (lane == 0)  hpart[bf0]     = hv;
        if (lane == 16) hpart[bf0 + 1] = hv;
    }
    __syncthreads();                                            // B5 (zfl dead)

    // ---- reconstruction hidden layer: ping-pong pipelined over k-batches ----
    {
        const float4* u4 = reinterpret_cast<const float4*>(bcu);   // [t][k-pairs][p]
        const float bb = rec_b1[tid];
        v2f accv[4] = {vsplat(bb), vsplat(bb), vsplat(bb), vsplat(bb)};
        const float* w1p = rec_W1 + tid;
        float wvA[8], wvB[8];
#pragma unroll
        for (int r = 0; r < 8; ++r) wvA[r] = w1p[r * Hh];

#define W1CONS(WV, KB) { \
        for (int rr = 0; rr < 4; ++rr) { \
            for (int t = 0; t < 4; ++t) { \
                const float4 U = u4[t * (Dd / 2) + 4 * (KB) + rr]; \
                accv[t] = vfmas(WV[2*rr],   vset(U.x, U.y), accv[t]); \
                accv[t] = vfmas(WV[2*rr+1], vset(U.z, U.w), accv[t]); \
            } } }

#pragma unroll 1
        for (int kb = 0; kb < Dd / 8; kb += 2) {
#pragma unroll
            for (int r = 0; r < 8; ++r)
                wvB[r] = w1p[((kb + 1) * 8 + r) * Hh];
            W1CONS(wvA, kb)
            if (kb + 2 < Dd / 8) {
#pragma unroll
                for (int r = 0; r < 8; ++r)
                    wvA[r] = w1p[((kb + 2) * 8 + r) * Hh];
            }
            W1CONS(wvB, kb + 1)
        }
#undef W1CONS
        // hbuf2 layout: [t][Hh][p] in lds_big
#pragma unroll
        for (int t = 0; t < 4; ++t) {
            v2f h = vset(fmaxf(accv[t].x, 0.f), fmaxf(accv[t].y, 0.f));
            *reinterpret_cast<v2f*>(lds_big + (t * Hh + tid) * 2) = h;
        }
    }
    __syncthreads();                                            // B6

    // ---- seg outputs: 96 threads, ping-pong pipelined over j-batches ----
    if (tid < Tt * SEGc) {
        const int t = tid / SEGc, s = tid - t * SEGc;
        const float4* h4 = reinterpret_cast<const float4*>(lds_big);  // [t][j-pairs][p]
        const float* w2p = rec_W2 + s;
        v2f acc2 = vsplat(rec_b2[s]);
        float wvA[8], wvB[8];
#pragma unroll
        for (int r = 0; r < 8; ++r) wvA[r] = w2p[r * SEGc];

#define W2CONS(WV, JB) { \
        for (int rr = 0; rr < 4; ++rr) { \
            const float4 H = h4[t * (Hh / 2) + 4 * (JB) + rr]; \
            acc2 = vfmas(WV[2*rr],   vset(H.x, H.y), acc2); \
            acc2 = vfmas(WV[2*rr+1], vset(H.z, H.w), acc2); } }

#pragma unroll 1
        for (int jb = 0; jb < Hh / 8; jb += 2) {
#pragma unroll
            for (int r = 0; r < 8; ++r)
                wvB[r] = w2p[((jb + 1) * 8 + r) * SEGc];
            W2CONS(wvA, jb)
            if (jb + 2 < Hh / 8) {
#pragma unroll
                for (int r = 0; r < 8; ++r)
                    wvA[r] = w2p[((jb + 2) * 8 + r) * SEGc];
            }
            W2CONS(wvB, jb + 1)
        }
#undef W2CONS
        const v2f rbv = vset(rb0v, rb1v);
        const v2f rwr = vset(frcp(rw0v), frcp(rw1v));
        const v2f sdv = vset(stdv0, stdv1);
        const v2f mnv = vset(mean0, mean1);
        const v2f res = (acc2 - rbv) * rwr * sdv + mnv;   // RevIN denorm
        *reinterpret_cast<float2*>(&out[(b * (Tt * SEGc) + tid) * Ff + f0]) =
            make_float2(res.x, res.y);
    }
#undef XS
#undef ZFL
}

// ---------------- deterministic hloss reduction ----------------
__global__ __launch_bounds__(256) void hloss_kernel(
    const float* __restrict__ hpart, float* __restrict__ out)
{
    __shared__ float sm[256];
    const int tid = threadIdx.x;
    float s = 0.f;
#pragma unroll 1
    for (int i = tid; i < BFc; i += 256) s += hpart[i];
    sm[tid] = s;
    __syncthreads();
#pragma unroll 1
    for (int off = 128; off > 0; off >>= 1) {
        if (tid < off) sm[tid] += sm[tid + off];
        __syncthreads();
    }
    if (tid == 0) out[Bb * Tt * SEGc * Ff] = sm[0] / (float)(BFc * Tt);
}

extern "C" void kernel_launch(void* const* d_in, const int* in_sizes, int n_in,
                              void* d_out, int out_size, void* d_ws, size_t ws_size,
                              hipStream_t stream) {
    const float* trend   = (const float*)d_in[0];
    const float* scoarse = (const float*)d_in[1];
    const float* sfine   = (const float*)d_in[2];
    const float* resid   = (const float*)d_in[3];
    const float* revin_w = (const float*)d_in[4];
    const float* revin_b = (const float*)d_in[5];
    const float* enc_W   = (const float*)d_in[6];
    const float* enc_b   = (const float*)d_in[7];
    const float* vel_W   = (const float*)d_in[8];
    const float* vel_b   = (const float*)d_in[9];
    const float* steps   = (const float*)d_in[10];
    const float* mobw    = (const float*)d_in[11];
    const float* rec_W1  = (const float*)d_in[12];
    const float* rec_b1  = (const float*)d_in[13];
    const float* rec_W2  = (const float*)d_in[14];
    const float* rec_b2  = (const float*)d_in[15];

    float* out = (float*)d_out;
    float* wsf = (float*)d_ws;           // hpart[8192]

    fused_kernel<<<BFc / 2, 256, 0, stream>>>(
        trend, scoarse, sfine, resid, revin_w, revin_b,
        enc_W, enc_b, vel_W, vel_b, steps, mobw,
        rec_W1, rec_b1, rec_W2, rec_b2,
        out, wsf);
    hloss_kernel<<<1, 256, 0, stream>>>(wsf, out);
}

// Round 13
// 221.212 us; speedup vs baseline: 1.0764x; 1.0612x over previous
//
#include <hip/hip_runtime.h>
#include <math.h>

#define EPSF 1e-5f
#define MAXNF (1.0f - 1e-5f)

constexpr int SEGc = 24;
constexpr int Nn   = 14;          // L / SEG
constexpr int NS   = Nn * SEGc;   // 336
constexpr int Tt   = 4;           // horizons
constexpr int Bb   = 32;
constexpr int Ll   = 336;
constexpr int Ff   = 256;
constexpr int Dd   = 128;
constexpr int Hh   = 256;
constexpr int BFc  = Bb * Ff;     // 8192

// v_init weight norm: 1 / (sum_{i=0}^{12} 0.9^i * 13)
constexpr float WNORM = 1.0f / (7.458134171670999f * 13.0f);
constexpr float LN09  = -0.10536051565782628f;   // ln(0.9)

// ---- packed fp32 (v_pk_fma_f32 on gfx90a+) ----
typedef float v2f __attribute__((ext_vector_type(2)));
__device__ __forceinline__ v2f vset(float a, float b){ v2f r; r.x=a; r.y=b; return r; }
__device__ __forceinline__ v2f vsplat(float s){ v2f r; r.x=s; r.y=s; return r; }
__device__ __forceinline__ v2f vfma(v2f a, v2f b, v2f c){
#if __has_builtin(__builtin_elementwise_fma)
    return __builtin_elementwise_fma(a, b, c);
#else
    return vset(fmaf(a.x, b.x, c.x), fmaf(a.y, b.y, c.y));
#endif
}
__device__ __forceinline__ v2f vfmas(float a, v2f b, v2f c){ return vfma(vsplat(a), b, c); }

// ---- fast math (tolerance 1.8e-2; these are ~1e-7 relative) ----
__device__ __forceinline__ float frcp(float x)  { return __builtin_amdgcn_rcpf(x); }
__device__ __forceinline__ float fsqrtf_(float x){ return __builtin_amdgcn_sqrtf(x); }
__device__ __forceinline__ float ftanh_pos(float x) {       // x >= 0
    const float e = __expf(fminf(2.f * x, 30.f));           // v_exp_f32
    return (e - 1.f) * frcp(e + 1.f);
}
__device__ __forceinline__ float fatanh01(float x) {        // 0 <= x <= MAXNF
    return 0.5f * __logf((1.f + x) * frcp(1.f - x));        // v_log_f32
}

// ---------------- fused kernel: one block (4 waves) per bf PAIR ----------------
// FINAL (R10 configuration — measured best: 253 us dispatch / 221.6 us bench).
// Structure: 2 bf per block (weights amortized 2x, f even/odd pair); wave =
// component; lane owns packed dim pair (v_pk_fma_f32); uniform scalar chains
// lane-parallelized (lanes 0-15 bf0 items, 16-31 bf1); LDS time-shared
// xs -> zfl -> hbuf (21 KB); XCD-chunked block swizzle (FETCH 175->26 MB);
// loops rolled where bodies have no runtime-indexed reg arrays (I$ footprint).
// Probes R11 (barrier cut: +8%) and R12 (load ping-pong: +7%) both regressed:
// the kernel is at the dependency-chain latency floor of this decomposition.
__global__ __launch_bounds__(256, 4) void fused_kernel(
    const float* __restrict__ trend, const float* __restrict__ scoarse,
    const float* __restrict__ sfine, const float* __restrict__ resid,
    const float* __restrict__ revin_w, const float* __restrict__ revin_b,
    const float* __restrict__ enc_W, const float* __restrict__ enc_b,
    const float* __restrict__ vel_W, const float* __restrict__ vel_b,
    const float* __restrict__ steps, const float* __restrict__ mobius_w,
    const float* __restrict__ rec_W1, const float* __restrict__ rec_b1,
    const float* __restrict__ rec_W2, const float* __restrict__ rec_b2,
    float* __restrict__ out, float* __restrict__ hpart)
{
    // XCD-chunking swizzle over 4096 pair-blocks (8 XCDs x 512 chunk).
    const int bid   = blockIdx.x;
    const int kpair = ((bid & 7) << 9) | (bid >> 3);   // 0..4095
    const int bf0   = kpair << 1;
    const int b     = bf0 >> 8;
    const int f0    = bf0 & 255;          // even
    const int tid   = threadIdx.x;
    const int wid   = tid >> 6;           // 0..3 = component
    const int lane  = tid & 63;
    const int gi    = lane & 15;          // item index within group
    const int pg    = (lane >> 4) & 1;    // group p (meaningful for lanes 0..31)

    __shared__ float lds_big[2 * 4 * Tt * Dd];   // 4096 floats = 16 KB, time-shared
    __shared__ float bcu[8 * Dd];                // [p][c]Dd bc; later uls2 [t][Dd][p]
    __shared__ float zfns[2][4][Tt];             // clipped norms per p
    __shared__ float red[16];

#define XS(p, c)     (lds_big + ((p) * 4 + (c)) * NS)                 // 8*336 floats
#define ZFL(p, i, t) (lds_big + (((p) * 4 + (i)) * Tt + (t)) * Dd)    // 4096 floats

    const float* cp = (wid == 0) ? trend : (wid == 1) ? scoarse
                    : (wid == 2) ? sfine : resid;

    // ---- stage raw rows: one float2 load serves both bf ----
#pragma unroll 1
    for (int i = lane; i < NS; i += 64) {
        const float2 v = *reinterpret_cast<const float2*>(&cp[(b * Ll + i) * Ff + f0]);
        XS(0, wid)[i] = v.x;
        XS(1, wid)[i] = v.y;
    }
    __syncthreads();                                            // B1

    // ---- RevIN stats for both bf ----
    float s0 = 0.f, q0 = 0.f, s1 = 0.f, q1 = 0.f;
#pragma unroll 1
    for (int l = tid; l < NS; l += 256) {
        const float x0 = XS(0,0)[l] + XS(0,1)[l] + XS(0,2)[l] + XS(0,3)[l];
        const float x1 = XS(1,0)[l] + XS(1,1)[l] + XS(1,2)[l] + XS(1,3)[l];
        s0 += x0; q0 += x0 * x0; s1 += x1; q1 += x1 * x1;
    }
#pragma unroll 1
    for (int off = 1; off < 64; off <<= 1) {
        s0 += __shfl_xor(s0, off, 64); q0 += __shfl_xor(q0, off, 64);
        s1 += __shfl_xor(s1, off, 64); q1 += __shfl_xor(q1, off, 64);
    }
    if (lane == 0) {
        red[wid] = s0; red[4 + wid] = q0; red[8 + wid] = s1; red[12 + wid] = q1;
    }
    __syncthreads();                                            // B2
    s0 = red[0] + red[1] + red[2] + red[3];
    q0 = red[4] + red[5] + red[6] + red[7];
    s1 = red[8] + red[9] + red[10] + red[11];
    q1 = red[12] + red[13] + red[14] + red[15];
    const float mean0 = s0 * (1.f / (float)NS);
    const float stdv0 = fsqrtf_(q0 * (1.f / (float)NS) - mean0 * mean0 + 1e-5f);
    const float mean1 = s1 * (1.f / (float)NS);
    const float stdv1 = fsqrtf_(q1 * (1.f / (float)NS) - mean1 * mean1 + 1e-5f);
    const float rw0v = revin_w[f0],     rb0v = revin_b[f0];
    const float rw1v = revin_w[f0 + 1], rb1v = revin_b[f0 + 1];
    const float aff0 = frcp(stdv0) * rw0v;
    const float kaf0 = 0.25f * (rb0v - mean0 * aff0);
    const float aff1 = frcp(stdv1) * rw1v;
    const float kaf1 = 0.25f * (rb1v - mean1 * aff1);

    // ================= branch (component c = wid, both bf) =================
    const int c = wid;
    const float4* xv40 = reinterpret_cast<const float4*>(XS(0, c));
    const float4* xv41 = reinterpret_cast<const float4*>(XS(1, c));
    const float* Wep = enc_W + c * SEGc * Dd + 2 * lane;
    const float* Wvp = vel_W + c * Dd * Dd + 2 * lane;

    v2f wreg[SEGc];
#pragma unroll
    for (int s = 0; s < SEGc; ++s)
        wreg[s] = *reinterpret_cast<const v2f*>(Wep + s * Dd);
    const v2f bev = *reinterpret_cast<const v2f*>(enc_b + c * Dd + 2 * lane);
    const v2f bvv = *reinterpret_cast<const v2f*>(vel_b + c * Dd + 2 * lane);

    v2f csv = vsplat(0.f);
#pragma unroll
    for (int s = 0; s < SEGc; ++s) csv += wreg[s];
    const v2f kb0v = vfmas(kaf0, csv, bev);
    const v2f kb1v = vfmas(kaf1, csv, bev);

    // --- Phase A: 28 encoder dots (14 per bf), packed dims ---
    v2f y0v[Nn], y1v[Nn];
#pragma unroll
    for (int n = 0; n < Nn; ++n) {
        v2f a0 = vsplat(0.f), a1 = vsplat(0.f);
#pragma unroll
        for (int q = 0; q < SEGc / 4; ++q) {
            const float4 xa = xv40[n * (SEGc / 4) + q];
            const float4 xb = xv41[n * (SEGc / 4) + q];
            a0 = vfmas(xa.x, wreg[4*q+0], a0); a1 = vfmas(xb.x, wreg[4*q+0], a1);
            a0 = vfmas(xa.y, wreg[4*q+1], a0); a1 = vfmas(xb.y, wreg[4*q+1], a1);
            a0 = vfmas(xa.z, wreg[4*q+2], a0); a1 = vfmas(xb.z, wreg[4*q+2], a1);
            a0 = vfmas(xa.w, wreg[4*q+3], a0); a1 = vfmas(xb.w, wreg[4*q+3], a1);
        }
        y0v[n] = vfmas(aff0, a0, kb0v);
        y1v[n] = vfmas(aff1, a1, kb1v);
    }

    // --- |y_n|^2 and neighbor dots for both bf: ONE rolled butterfly (54 vals) ---
    float qnv[2][Nn], rdv[2][Nn - 1];
#pragma unroll
    for (int n = 0; n < Nn; ++n) {
        qnv[0][n] = fmaf(y0v[n].y, y0v[n].y, y0v[n].x * y0v[n].x);
        qnv[1][n] = fmaf(y1v[n].y, y1v[n].y, y1v[n].x * y1v[n].x);
    }
#pragma unroll
    for (int n = 1; n < Nn; ++n) {
        rdv[0][n - 1] = fmaf(y0v[n-1].y, y0v[n].y, y0v[n-1].x * y0v[n].x);
        rdv[1][n - 1] = fmaf(y1v[n-1].y, y1v[n].y, y1v[n-1].x * y1v[n].x);
    }
#pragma unroll 1
    for (int off = 1; off < 64; off <<= 1) {
#pragma unroll
        for (int n = 0; n < Nn; ++n) {
            qnv[0][n] += __shfl_xor(qnv[0][n], off, 64);
            qnv[1][n] += __shfl_xor(qnv[1][n], off, 64);
        }
#pragma unroll
        for (int j = 0; j < Nn - 1; ++j) {
            rdv[0][j] += __shfl_xor(rdv[0][j], off, 64);
            rdv[1][j] += __shfl_xor(rdv[1][j], off, 64);
        }
    }
    float qsel0 = qnv[0][0], qsel1 = qnv[1][0];
#pragma unroll
    for (int n = 1; n < Nn; ++n) {
        qsel0 = (gi == n) ? qnv[0][n] : qsel0;
        qsel1 = (gi == n) ? qnv[1][n] : qsel1;
    }
    const float qn_own = pg ? qsel1 : qsel0;
    float rsel0 = rdv[0][0], rsel1 = rdv[1][0];
#pragma unroll
    for (int n = 1; n < Nn - 1; ++n) {
        rsel0 = (gi == n) ? rdv[0][n] : rsel0;
        rsel1 = (gi == n) ? rdv[1][n] : rsel1;
    }
    const float rd_own = pg ? rsel1 : rsel0;

    // --- per-segment projection, one transcendental pass for both bf ---
    const float vn = fsqrtf_(fmaxf(qn_own, EPSF * EPSF));
    const float th = ftanh_pos(vn);
    float s_own = th * frcp(vn);
    float nrm = th;
    if (nrm > MAXNF) { s_own *= MAXNF * frcp(nrm); nrm = MAXNF; }
    const float zn2_own = nrm * nrm;

    // --- logmap step j at lane (16p + j), j = 1..13, one pass ---
    const float s_prev   = __shfl(s_own,   lane - 1, 64);
    const float zn2_prev = __shfl(zn2_own, lane - 1, 64);
    const float rd_prev  = __shfl(rd_own,  lane - 1, 64);   // rd[j-1] at lane j

    const float xyv  = -(s_prev * s_own * rd_prev);
    const float x2v  = zn2_prev, yy2 = zn2_own;
    const float c1v  = 1.f + 2.f * xyv + yy2;
    const float c2v  = 1.f - x2v;
    const float rdenv = frcp(fmaxf(1.f + 2.f * xyv + x2v * yy2, EPSF));
    const float un2 = rdenv * rdenv *
        (c1v * c1v * x2v + 2.f * c1v * c2v * xyv + c2v * c2v * yy2);
    const float un  = fsqrtf_(fmaxf(un2, EPSF * EPSF));
    const float lf  = fmaxf(1.f - x2v, EPSF);               // 2/lam
    const float gml = lf * fatanh01(fminf(un, MAXNF)) * frcp(un);
    const float wj  = WNORM * __expf(LN09 * (float)(13 - gi));  // 0.9^(13-j)
    const float gw  = wj * gml * rdenv;
    const float g1_own = -gw * c1v * s_prev;   // contribution to coef[j-1]
    const float g2_own =  gw * c2v * s_own;    // contribution to coef[j]

    // --- v_init for both bf (packed dims) ---
    v2f vi0v = vsplat(0.f), vi1v = vsplat(0.f);
#pragma unroll
    for (int n = 0; n < Nn; ++n) {
        float cf0 = 0.f, cf1 = 0.f;
        if (n >= 1)      { cf0 = __shfl(g2_own, n, 64);       cf1 = __shfl(g2_own, 16 + n, 64); }
        if (n <= Nn - 2) { cf0 += __shfl(g1_own, n + 1, 64);  cf1 += __shfl(g1_own, 17 + n, 64); }
        vi0v = vfmas(cf0, y0v[n], vi0v);
        vi1v = vfmas(cf1, y1v[n], vi1v);
    }
    const float scl0 = __shfl(s_own, 13, 64),  x2l0 = __shfl(zn2_own, 13, 64);
    const float scl1 = __shfl(s_own, 29, 64),  x2l1 = __shfl(zn2_own, 29, 64);
    const v2f z0lv = y0v[Nn-1] * scl0;   // z_last bf0 (2 dims)
    const v2f z1lv = y1v[Nn-1] * scl1;   // z_last bf1

    // --- logmap0(v_init) -> bcu ---
    float vin20 = fmaf(vi0v.y, vi0v.y, vi0v.x * vi0v.x);
    float vin21 = fmaf(vi1v.y, vi1v.y, vi1v.x * vi1v.x);
#pragma unroll 1
    for (int off = 1; off < 64; off <<= 1) {
        vin20 += __shfl_xor(vin20, off, 64);
        vin21 += __shfl_xor(vin21, off, 64);
    }
    const float vinn0 = fsqrtf_(fmaxf(vin20, EPSF * EPSF));
    const float lgv0  = fatanh01(fminf(vinn0, MAXNF)) * frcp(vinn0);
    const float vinn1 = fsqrtf_(fmaxf(vin21, EPSF * EPSF));
    const float lgv1  = fatanh01(fminf(vinn1, MAXNF)) * frcp(vinn1);
    *reinterpret_cast<v2f*>(&bcu[(0 * 4 + c) * Dd + 2 * lane]) = vi0v * lgv0;
    *reinterpret_cast<v2f*>(&bcu[(4 + c) * Dd + 2 * lane])     = vi1v * lgv1;
    __syncthreads();                                            // B3 (xs dead)

    // --- vel matmul: weight loads shared across both bf, packed dims ---
    v2f m0v = bvv, m1v = bvv;
    {
        const float4* bc40 = reinterpret_cast<const float4*>(bcu + (0 * 4 + c) * Dd);
        const float4* bc41 = reinterpret_cast<const float4*>(bcu + (4 + c) * Dd);
#pragma unroll 1
        for (int kb = 0; kb < Dd / 8; ++kb) {      // 8-deep load batches
            v2f w[8];
#pragma unroll
            for (int r = 0; r < 8; ++r)
                w[r] = *reinterpret_cast<const v2f*>(Wvp + (8 * kb + r) * Dd);
            const float4 ta0 = bc40[2*kb], tb0 = bc40[2*kb+1];
            const float4 ta1 = bc41[2*kb], tb1 = bc41[2*kb+1];
            m0v = vfmas(ta0.x, w[0], m0v); m1v = vfmas(ta1.x, w[0], m1v);
            m0v = vfmas(ta0.y, w[1], m0v); m1v = vfmas(ta1.y, w[1], m1v);
            m0v = vfmas(ta0.z, w[2], m0v); m1v = vfmas(ta1.z, w[2], m1v);
            m0v = vfmas(ta0.w, w[3], m0v); m1v = vfmas(ta1.w, w[3], m1v);
            m0v = vfmas(tb0.x, w[4], m0v); m1v = vfmas(tb1.x, w[4], m1v);
            m0v = vfmas(tb0.y, w[5], m0v); m1v = vfmas(tb1.y, w[5], m1v);
            m0v = vfmas(tb0.z, w[6], m0v); m1v = vfmas(tb1.z, w[6], m1v);
            m0v = vfmas(tb0.w, w[7], m0v); m1v = vfmas(tb1.w, w[7], m1v);
        }
    }
    float mn20 = fmaf(m0v.y, m0v.y, m0v.x * m0v.x);
    float zdm0 = fmaf(z0lv.y, m0v.y, z0lv.x * m0v.x);
    float mn21 = fmaf(m1v.y, m1v.y, m1v.x * m1v.x);
    float zdm1 = fmaf(z1lv.y, m1v.y, z1lv.x * m1v.x);
#pragma unroll 1
    for (int off = 1; off < 64; off <<= 1) {
        mn20 += __shfl_xor(mn20, off, 64); zdm0 += __shfl_xor(zdm0, off, 64);
        mn21 += __shfl_xor(mn21, off, 64); zdm1 += __shfl_xor(zdm1, off, 64);
    }

    // --- expmap0 of velocity + horizon scalars, lane-parallel over (p, t) ---
    const float sig = frcp(1.f + __expf(-steps[c]));
    {
        const float mn2g = pg ? mn21 : mn20;
        const float zdmg = pg ? zdm1 : zdm0;
        const float x2lg = pg ? x2l1 : x2l0;
        const float mng  = fsqrtf_(fmaxf(mn2g, EPSF * EPSF));
        const float thg  = ftanh_pos(mng);
        float sc2g = thg * frcp(mng);
        float v0ng = thg;
        if (v0ng > MAXNF) { sc2g *= MAXNF * frcp(v0ng); v0ng = MAXNF; }
        const float v0n2g  = mn2g * sc2g * sc2g;
        const float zdotvg = sc2g * zdmg;
        const float lamxg  = 2.f * frcp(fmaxf(1.f - x2lg, EPSF));

        const float alpha = sig * (float)(gi + 1);
        const float vtn2  = alpha * alpha * v0n2g;
        const float vtn   = fsqrtf_(fmaxf(vtn2, EPSF * EPSF));
        const float gg    = ftanh_pos(0.5f * lamxg * vtn);
        const float cyc   = gg * alpha * frcp(vtn);
        const float y2    = cyc * cyc * v0n2g;
        const float xy    = cyc * zdotvg;
        const float c1 = 1.f + 2.f * xy + y2;
        const float c2 = 1.f - x2lg;
        const float rden = frcp(fmaxf(1.f + 2.f * xy + x2lg * y2, EPSF));
        float rn2 = rden * rden *
            (c1 * c1 * x2lg + 2.f * c1 * c2 * xy + c2 * c2 * y2);
        float rn = fsqrtf_(fmaxf(rn2, EPSF * EPSF));
        float sclip = 1.f;
        if (rn > MAXNF) { sclip = MAXNF * frcp(rn); rn = MAXNF; }
        const float At_own = c1 * rden * sclip;         // coeff of z_last
        const float Bt_own = c2 * cyc * rden * sclip;   // coeff of v0t
        if (lane < 32 && gi < Tt) zfns[pg][c][gi] = rn;

        const float sc2_0 = __shfl(sc2g, 0, 64), sc2_1 = __shfl(sc2g, 16, 64);
        const v2f v0d0 = m0v * sc2_0;   // v0t bf0
        const v2f v0d1 = m1v * sc2_1;   // v0t bf1
#pragma unroll 1
        for (int t = 0; t < Tt; ++t) {
            const float A0 = __shfl(At_own, t, 64),      B0 = __shfl(Bt_own, t, 64);
            const float A1 = __shfl(At_own, 16 + t, 64), B1 = __shfl(Bt_own, 16 + t, 64);
            *reinterpret_cast<v2f*>(ZFL(0, c, t) + 2 * lane) = vfmas(A0, z0lv, v0d0 * B0);
            *reinterpret_cast<v2f*>(ZFL(1, c, t) + 2 * lane) = vfmas(A1, z1lv, v0d1 * B1);
        }
    }
    __syncthreads();                                            // B4 (bc dead)

    // ======= Mobius fusion via Gram matrices: wave wid = horizon t, both bf =======
    {
        float mwa = mobius_w[0], mwb = mobius_w[1], mwc = mobius_w[2], mwd = mobius_w[3];
        const float mx = fmaxf(fmaxf(mwa, mwb), fmaxf(mwc, mwd));
        mwa = __expf(mwa - mx); mwb = __expf(mwb - mx);
        mwc = __expf(mwc - mx); mwd = __expf(mwd - mx);
        const float rse = frcp(mwa + mwb + mwc + mwd);
        const float mw[4] = {mwa * rse, mwb * rse, mwc * rse, mwd * rse};

        const int t = wid;
        v2f e0[4], e1[4];
#pragma unroll
        for (int i = 0; i < 4; ++i) {
            e0[i] = *reinterpret_cast<const v2f*>(ZFL(0, i, t) + 2 * lane);
            e1[i] = *reinterpret_cast<const v2f*>(ZFL(1, i, t) + 2 * lane);
        }
        float gp[12];
        gp[0]  = fmaf(e0[0].y, e0[1].y, e0[0].x * e0[1].x);
        gp[1]  = fmaf(e0[0].y, e0[2].y, e0[0].x * e0[2].x);
        gp[2]  = fmaf(e0[0].y, e0[3].y, e0[0].x * e0[3].x);
        gp[3]  = fmaf(e0[1].y, e0[2].y, e0[1].x * e0[2].x);
        gp[4]  = fmaf(e0[1].y, e0[3].y, e0[1].x * e0[3].x);
        gp[5]  = fmaf(e0[2].y, e0[3].y, e0[2].x * e0[3].x);
        gp[6]  = fmaf(e1[0].y, e1[1].y, e1[0].x * e1[1].x);
        gp[7]  = fmaf(e1[0].y, e1[2].y, e1[0].x * e1[2].x);
        gp[8]  = fmaf(e1[0].y, e1[3].y, e1[0].x * e1[3].x);
        gp[9]  = fmaf(e1[1].y, e1[2].y, e1[1].x * e1[2].x);
        gp[10] = fmaf(e1[1].y, e1[3].y, e1[1].x * e1[3].x);
        gp[11] = fmaf(e1[2].y, e1[3].y, e1[2].x * e1[3].x);
#pragma unroll 1
        for (int off = 1; off < 64; off <<= 1) {
#pragma unroll
            for (int k = 0; k < 12; ++k) gp[k] += __shfl_xor(gp[k], off, 64);
        }

        // mob_smul scales: one transcendental pass for 8 (p,i) at lanes 0-3,16-19
        const int il = lane & 3;
        float mwv_own = mw[0];
        mwv_own = (il == 1) ? mw[1] : mwv_own;
        mwv_own = (il == 2) ? mw[2] : mwv_own;
        mwv_own = (il == 3) ? mw[3] : mwv_own;
        const float xn_own = zfns[pg][il][t];
        const float smc = ftanh_pos(mwv_own * fatanh01(xn_own)) * frcp(xn_own);
        float smv[2][4];
#pragma unroll
        for (int i = 0; i < 4; ++i) {
            smv[0][i] = __shfl(smc, i, 64);
            smv[1][i] = __shfl(smc, 16 + i, 64);
        }

#pragma unroll
        for (int p = 0; p < 2; ++p) {
            const float xn0 = zfns[p][0][t], xn1 = zfns[p][1][t];
            const float xn2 = zfns[p][2][t], xn3 = zfns[p][3][t];
            const float Gd[4] = {xn0*xn0, xn1*xn1, xn2*xn2, xn3*xn3};
            const float G[4][4] = {
                {Gd[0], gp[6*p+0], gp[6*p+1], gp[6*p+2]},
                {gp[6*p+0], Gd[1], gp[6*p+3], gp[6*p+4]},
                {gp[6*p+1], gp[6*p+3], Gd[2], gp[6*p+5]},
                {gp[6*p+2], gp[6*p+4], gp[6*p+5], Gd[3]}};
            float a0 = smv[p][0], a1 = 0.f, a2 = 0.f, a3 = 0.f;
            float cn2 = smv[p][0] * smv[p][0] * Gd[0];
#pragma unroll
            for (int i = 1; i < 4; ++i) {
                const float si = smv[p][i];
                const float xy = si * (a0*G[0][i] + a1*G[1][i] + a2*G[2][i] + a3*G[3][i]);
                const float y2 = si * si * Gd[i];
                const float c1 = 1.f + 2.f * xy + y2;
                const float c2 = 1.f - cn2;
                const float rden = frcp(fmaxf(1.f + 2.f * xy + cn2 * y2, EPSF));
                const float f1 = rden * c1, f2 = rden * c2 * si;
                a0 *= f1; a1 *= f1; a2 *= f1; a3 *= f1;
                if (i == 1) a1 += f2; else if (i == 2) a2 += f2; else a3 += f2;
                cn2 = rden * rden * (c1*c1*cn2 + 2.f*c1*c2*xy + c2*c2*y2);
            }
            float cn = fsqrtf_(fmaxf(cn2, EPSF * EPSF));
            float csc = 1.f;
            if (cn > MAXNF) { csc = MAXNF * frcp(cn); cn = MAXNF; }
            const float lg = fatanh01(cn) * frcp(cn) * csc;
            const v2f* ee = p ? e1 : e0;
            v2f uv = ee[0] * a0;
            uv = vfmas(a1, ee[1], uv);
            uv = vfmas(a2, ee[2], uv);
            uv = vfmas(a3, ee[3], uv);
            uv = uv * lg;
            // uls2 layout: [t][Dd][p] -> index (t*Dd + d)*2 + p (in bcu)
            const int ub = (t * Dd + 2 * lane) * 2 + p;
            bcu[ub]     = uv.x;
            bcu[ub + 2] = uv.y;
        }
    }

    // ---- hinge-loss partials: wave 0, lanes 0-15 bf0, 16-31 bf1 ----
    if (wid == 0) {
        float ddv = 0.f;
        if (lane < 32)
            ddv = 2.f * fatanh01(zfns[pg][lane & 3][gi >> 2]);
        const float ddn = __shfl(ddv, lane + 1, 64);
        float hv = ((lane < 32) && ((lane & 3) != 3))
                 ? fmaxf(ddv - ddn + 0.1f, 0.f) : 0.f;
#pragma unroll 1
        for (int off = 1; off < 16; off <<= 1) hv += __shfl_xor(hv, off, 64);
        if (lane == 0)  hpart[bf0]     = hv;
        if (lane == 16) hpart[bf0 + 1] = hv;
    }
    __syncthreads();                                            // B5 (zfl dead)

    // ---- reconstruction hidden layer: thread tid = hidden j, p-packed ----
    {
        const float4* u4 = reinterpret_cast<const float4*>(bcu);   // [t][k-pairs][p]
        const float bb = rec_b1[tid];
        v2f accv[4] = {vsplat(bb), vsplat(bb), vsplat(bb), vsplat(bb)};
        const float* w1p = rec_W1 + tid;
#pragma unroll 1
        for (int kb = 0; kb < Dd / 8; ++kb) {      // 8-deep weight load batches
            float wv[8];
#pragma unroll
            for (int r = 0; r < 8; ++r) wv[r] = w1p[(8 * kb + r) * Hh];
#pragma unroll
            for (int rr = 0; rr < 4; ++rr) {       // k-pairs (8kb+2rr, 8kb+2rr+1)
#pragma unroll
                for (int t = 0; t < 4; ++t) {
                    const float4 U = u4[t * (Dd / 2) + 4 * kb + rr];
                    accv[t] = vfmas(wv[2*rr],   vset(U.x, U.y), accv[t]);
                    accv[t] = vfmas(wv[2*rr+1], vset(U.z, U.w), accv[t]);
                }
            }
        }
        // hbuf2 layout: [t][Hh][p] in lds_big
#pragma unroll
        for (int t = 0; t < 4; ++t) {
            v2f h = vset(fmaxf(accv[t].x, 0.f), fmaxf(accv[t].y, 0.f));
            *reinterpret_cast<v2f*>(lds_big + (t * Hh + tid) * 2) = h;
        }
    }
    __syncthreads();                                            // B6

    // ---- seg outputs: 96 threads, each handles (t,s) for BOTH bf ----
    if (tid < Tt * SEGc) {
        const int t = tid / SEGc, s = tid - t * SEGc;
        const float4* h4 = reinterpret_cast<const float4*>(lds_big);  // [t][j-pairs][p]
        const float* w2p = rec_W2 + s;
        v2f acc2 = vsplat(rec_b2[s]);
#pragma unroll 1
        for (int jb = 0; jb < Hh / 8; ++jb) {
            float wv[8];
#pragma unroll
            for (int r = 0; r < 8; ++r) wv[r] = w2p[(8 * jb + r) * SEGc];
#pragma unroll
            for (int rr = 0; rr < 4; ++rr) {       // j-pairs (8jb+2rr, 8jb+2rr+1)
                const float4 H = h4[t * (Hh / 2) + 4 * jb + rr];
                acc2 = vfmas(wv[2*rr],   vset(H.x, H.y), acc2);
                acc2 = vfmas(wv[2*rr+1], vset(H.z, H.w), acc2);
            }
        }
        const v2f rbv = vset(rb0v, rb1v);
        const v2f rwr = vset(frcp(rw0v), frcp(rw1v));
        const v2f sdv = vset(stdv0, stdv1);
        const v2f mnv = vset(mean0, mean1);
        const v2f res = (acc2 - rbv) * rwr * sdv + mnv;   // RevIN denorm
        *reinterpret_cast<float2*>(&out[(b * (Tt * SEGc) + tid) * Ff + f0]) =
            make_float2(res.x, res.y);
    }
#undef XS
#undef ZFL
}

// ---------------- deterministic hloss reduction ----------------
__global__ __launch_bounds__(256) void hloss_kernel(
    const float* __restrict__ hpart, float* __restrict__ out)
{
    __shared__ float sm[256];
    const int tid = threadIdx.x;
    float s = 0.f;
#pragma unroll 1
    for (int i = tid; i < BFc; i += 256) s += hpart[i];
    sm[tid] = s;
    __syncthreads();
#pragma unroll 1
    for (int off = 128; off > 0; off >>= 1) {
        if (tid < off) sm[tid] += sm[tid + off];
        __syncthreads();
    }
    if (tid == 0) out[Bb * Tt * SEGc * Ff] = sm[0] / (float)(BFc * Tt);
}

extern "C" void kernel_launch(void* const* d_in, const int* in_sizes, int n_in,
                              void* d_out, int out_size, void* d_ws, size_t ws_size,
                              hipStream_t stream) {
    const float* trend   = (const float*)d_in[0];
    const float* scoarse = (const float*)d_in[1];
    const float* sfine   = (const float*)d_in[2];
    const float* resid   = (const float*)d_in[3];
    const float* revin_w = (const float*)d_in[4];
    const float* revin_b = (const float*)d_in[5];
    const float* enc_W   = (const float*)d_in[6];
    const float* enc_b   = (const float*)d_in[7];
    const float* vel_W   = (const float*)d_in[8];
    const float* vel_b   = (const float*)d_in[9];
    const float* steps   = (const float*)d_in[10];
    const float* mobw    = (const float*)d_in[11];
    const float* rec_W1  = (const float*)d_in[12];
    const float* rec_b1  = (const float*)d_in[13];
    const float* rec_W2  = (const float*)d_in[14];
    const float* rec_b2  = (const float*)d_in[15];

    float* out = (float*)d_out;
    float* wsf = (float*)d_ws;           // hpart[8192]

    fused_kernel<<<BFc / 2, 256, 0, stream>>>(
        trend, scoarse, sfine, resid, revin_w, revin_b,
        enc_W, enc_b, vel_W, vel_b, steps, mobw,
        rec_W1, rec_b1, rec_W2, rec_b2,
        out, wsf);
    hloss_kernel<<<1, 256, 0, stream>>>(wsf, out);
}